// Round 1
// baseline (403.695 us; speedup 1.0000x reference)
//
#include <hip/hip_runtime.h>
#include <hip/hip_bf16.h>

typedef __attribute__((ext_vector_type(8))) short bf16x8;   // 8 bf16 = 4 VGPRs
typedef __attribute__((ext_vector_type(4))) float f32x4;    // MFMA C/D frag

#define Qn 4096
#define Mn 8192
#define Dn 128
#define NW 8                 // waves per block
#define MSLICE (Mn / NW)     // 1024 columns per wave
#define NT 64                // columns per iteration

__device__ __forceinline__ unsigned short f2bf(float x) {
  __hip_bfloat16 h = __float2bfloat16(x);
  return *reinterpret_cast<unsigned short*>(&h);
}

// Cast Q*(1/sqrt(D)) -> bf16, K -> bf16, and K^T -> bf16 (for contiguous PV B-fragments)
__global__ void prep_kernel(const float* __restrict__ Q,
                            const float* __restrict__ K,
                            unsigned short* __restrict__ Qs,
                            unsigned short* __restrict__ Kb,
                            unsigned short* __restrict__ Vt) {
  int idx = blockIdx.x * blockDim.x + threadIdx.x;     // 0 .. Mn*Dn-1
  const float scale = 0.088388347648318447f;           // 1/sqrt(128)
  if (idx < Qn * Dn) Qs[idx] = f2bf(Q[idx] * scale);
  float v = K[idx];
  Kb[idx] = f2bf(v);
  int m = idx >> 7, d = idx & 127;
  Vt[d * Mn + m] = f2bf(v);                            // Vt[d][m] = K[m][d]
}

// One block = 16 Q-rows. 8 waves, each owns M-slice of 1024 cols.
// No online-softmax rescaling: |logit| <= ~6, exp() cannot overflow fp32.
__global__ __launch_bounds__(512, 1)
void attn_kernel(const float* __restrict__ W,
                 const unsigned short* __restrict__ Qs,
                 const unsigned short* __restrict__ Kb,
                 const unsigned short* __restrict__ Vt,
                 float* __restrict__ out) {
  // Per-wave P tile (16x64 bf16), double-buffered, row padded 64->72 (+8 bf16)
  // to keep 16B alignment for ds_read_b128 and break the 16-way bank conflict.
  __shared__ __align__(16) unsigned short Plds[NW][2][16][72];
  __shared__ float Ored[16][Dn];
  __shared__ float lred[16];

  const int tid  = threadIdx.x;
  const int wave = tid >> 6;
  const int lane = tid & 63;
  const int l    = lane & 15;   // MFMA "lane&15" index
  const int quad = lane >> 4;   // MFMA quad
  const int qb   = blockIdx.x * 16;

  for (int i = tid; i < 16 * Dn; i += 512) ((float*)Ored)[i] = 0.0f;
  if (tid < 16) lred[tid] = 0.0f;
  __syncthreads();

  // Persistent Q A-fragments: A[m=l][k=quad*8+j], k-chunks kk=0..3 cover D=128.
  bf16x8 aq[4];
  {
    const unsigned short* qrow = Qs + (qb + l) * Dn + quad * 8;
#pragma unroll
    for (int kk = 0; kk < 4; ++kk)
      aq[kk] = *reinterpret_cast<const bf16x8*>(qrow + 32 * kk);
  }

  f32x4 O[8];                       // O accum: rows quad*4+r, cols 16n+l
#pragma unroll
  for (int n = 0; n < 8; ++n) O[n] = (f32x4){0.f, 0.f, 0.f, 0.f};
  float lsum[4] = {0.f, 0.f, 0.f, 0.f};  // per-row (quad*4+r) partial denominators

  const int mbeg = wave * MSLICE;
  int buf = 0;
  for (int m0 = mbeg; m0 < mbeg + MSLICE; m0 += NT, buf ^= 1) {
    // ---- S = (Q/sqrt(d)) K^T : 16 rows x 64 cols, 4 col-chunks a ----
    f32x4 S[4];
#pragma unroll
    for (int a = 0; a < 4; ++a) S[a] = (f32x4){0.f, 0.f, 0.f, 0.f};
#pragma unroll
    for (int a = 0; a < 4; ++a) {
      // B[k=d][n=m]: lane reads K[m0+16a+l][32kk + quad*8 .. +7] (contiguous 16B)
      const unsigned short* krow = Kb + (size_t)(m0 + 16 * a + l) * Dn + quad * 8;
#pragma unroll
      for (int kk = 0; kk < 4; ++kk) {
        bf16x8 bk = *reinterpret_cast<const bf16x8*>(krow + 32 * kk);
        S[a] = __builtin_amdgcn_mfma_f32_16x16x32_bf16(aq[kk], bk, S[a], 0, 0, 0);
      }
    }
    // ---- logits = S*W, p = exp(logit); C-layout: row=quad*4+r, col=16a+l ----
#pragma unroll
    for (int a = 0; a < 4; ++a) {
#pragma unroll
      for (int r = 0; r < 4; ++r) {
        float wv = W[(size_t)(qb + quad * 4 + r) * Mn + (m0 + 16 * a + l)];
        float p = __expf(S[a][r] * wv);
        lsum[r] += p;
        Plds[wave][buf][quad * 4 + r][16 * a + l] = f2bf(p);
      }
    }
    // Same-wave LDS RAW: force all ds_writes to retire before the A-frag reads.
    asm volatile("s_waitcnt lgkmcnt(0)" ::: "memory");
    // ---- O += P V : A-frag P[m=l][k=32kk+quad*8+j], B-frag Vt rows (16B reads)
#pragma unroll
    for (int kk = 0; kk < 2; ++kk) {
      bf16x8 pa = *reinterpret_cast<const bf16x8*>(&Plds[wave][buf][l][32 * kk + quad * 8]);
#pragma unroll
      for (int n = 0; n < 8; ++n) {
        bf16x8 bv = *reinterpret_cast<const bf16x8*>(
            Vt + (size_t)(16 * n + l) * Mn + (m0 + 32 * kk + quad * 8));
        O[n] = __builtin_amdgcn_mfma_f32_16x16x32_bf16(pa, bv, O[n], 0, 0, 0);
      }
    }
  }

  // Row-sum: reduce lsum over the 16 lanes of the quad (cols live across lanes).
#pragma unroll
  for (int r = 0; r < 4; ++r) {
#pragma unroll
    for (int off = 1; off < 16; off <<= 1)
      lsum[r] += __shfl_xor(lsum[r], off, 64);
  }

  // Cross-wave combine (plain sums -- no rescaling needed).
#pragma unroll
  for (int n = 0; n < 8; ++n)
#pragma unroll
    for (int r = 0; r < 4; ++r)
      atomicAdd(&Ored[quad * 4 + r][16 * n + l], O[n][r]);
  if (l == 0) {
#pragma unroll
    for (int r = 0; r < 4; ++r)
      atomicAdd(&lred[quad * 4 + r], lsum[r]);
  }
  __syncthreads();

  // out = O / l, coalesced store.
  for (int i = tid; i < 16 * Dn; i += 512) {
    int row = i >> 7, d = i & 127;
    out[(size_t)(qb + row) * Dn + d] = Ored[row][d] / lred[row];
  }
}

extern "C" void kernel_launch(void* const* d_in, const int* in_sizes, int n_in,
                              void* d_out, int out_size, void* d_ws, size_t ws_size,
                              hipStream_t stream) {
  const float* Q = (const float*)d_in[0];          // [4096,128]
  const float* K = (const float*)d_in[1];          // [8192,128]
  const float* W = (const float*)d_in[2];          // [4096,8192]
  float* out = (float*)d_out;                      // [4096,128]

  unsigned short* Qs = (unsigned short*)d_ws;      // 1 MB
  unsigned short* Kb = Qs + (size_t)Qn * Dn;       // 2 MB
  unsigned short* Vt = Kb + (size_t)Mn * Dn;       // 2 MB  (total 5 MB of ws)

  prep_kernel<<<(Mn * Dn) / 256, 256, 0, stream>>>(Q, K, Qs, Kb, Vt);
  attn_kernel<<<Qn / 16, 512, 0, stream>>>(W, Qs, Kb, Vt, out);
}

// Round 2
// 363.525 us; speedup vs baseline: 1.1105x; 1.1105x over previous
//
#include <hip/hip_runtime.h>
#include <hip/hip_bf16.h>

typedef __attribute__((ext_vector_type(8))) short bf16x8;   // 8 bf16 = 4 VGPRs
typedef __attribute__((ext_vector_type(4))) float f32x4;    // MFMA C/D frag

#define Qn 4096
#define Mn 8192
#define Dn 128
#define NWA 4                    // waves per block
#define MSPLIT 4                 // M split across blockIdx.y
#define BCOLS (Mn / MSPLIT)      // 2048 cols per block
#define WCOLS (BCOLS / NWA)      // 512 cols per wave
#define NT 64                    // cols per iteration
#define NIT (WCOLS / NT)         // 8 iterations per wave

__device__ __forceinline__ unsigned short f2bf(float x) {
  __hip_bfloat16 h = __float2bfloat16(x);
  return *reinterpret_cast<unsigned short*>(&h);
}

__global__ void zero_kernel(float4* __restrict__ p, int n4) {
  int i = blockIdx.x * blockDim.x + threadIdx.x;
  if (i < n4) p[i] = make_float4(0.f, 0.f, 0.f, 0.f);
}

// float4 -> ushort4 bf16 casts for Qs (scaled) and Kb
__global__ void cast_kernel(const float4* __restrict__ Q4,
                            const float4* __restrict__ K4,
                            ushort4* __restrict__ Qs,
                            ushort4* __restrict__ Kb) {
  int i = blockIdx.x * blockDim.x + threadIdx.x;   // 0 .. Mn*Dn/4-1
  const float s = 0.088388347648318447f;           // 1/sqrt(128)
  float4 k = K4[i];
  Kb[i] = make_ushort4(f2bf(k.x), f2bf(k.y), f2bf(k.z), f2bf(k.w));
  if (i < Qn * Dn / 4) {
    float4 q = Q4[i];
    Qs[i] = make_ushort4(f2bf(q.x * s), f2bf(q.y * s), f2bf(q.z * s), f2bf(q.w * s));
  }
}

// LDS-tiled transpose: K[8192][128] f32 -> Vt[128][8192] bf16 (coalesced both sides)
__global__ void transpose_kernel(const float* __restrict__ K,
                                 unsigned short* __restrict__ Vt) {
  __shared__ float tile[64][65];
  const int m0 = blockIdx.x * 64, d0 = blockIdx.y * 64;
  const int t = threadIdx.x;
  const int r = t >> 4, c4 = (t & 15) * 4;
#pragma unroll
  for (int rr = 0; rr < 64; rr += 16) {
    float4 v = *reinterpret_cast<const float4*>(&K[(size_t)(m0 + r + rr) * Dn + d0 + c4]);
    tile[r + rr][c4 + 0] = v.x; tile[r + rr][c4 + 1] = v.y;
    tile[r + rr][c4 + 2] = v.z; tile[r + rr][c4 + 3] = v.w;
  }
  __syncthreads();
#pragma unroll
  for (int rep = 0; rep < 2; ++rep) {
    int w = t + rep * 256;
    int i = w >> 3;            // output row (d offset) 0..63
    int g = (w & 7) * 8;       // col group of 8
    unsigned short tmp[8];
#pragma unroll
    for (int k = 0; k < 8; ++k) tmp[k] = f2bf(tile[g + k][i]);
    *reinterpret_cast<uint4*>(&Vt[(size_t)(d0 + i) * Mn + m0 + g]) =
        *reinterpret_cast<uint4*>(tmp);
  }
}

// One block: 16 Q-rows x 2048 M-cols (blockIdx.y selects M quarter). 4 waves.
// No online-softmax rescaling: |logit| <= ~6, exp() cannot overflow fp32;
// partials combine by plain addition (global atomicAdd), finalize divides.
__global__ __launch_bounds__(256, 4)
void attn_kernel(const float* __restrict__ W,
                 const unsigned short* __restrict__ Qs,
                 const unsigned short* __restrict__ Kb,
                 const unsigned short* __restrict__ Vt,
                 float* __restrict__ Oacc,
                 float* __restrict__ Lacc) {
  // Per-wave P tile (16x64 bf16), row padded 64->72 for 16B-aligned ds_read_b128.
  // Single-buffered: DS ops from one wave complete in order, and we lgkmcnt(0)
  // before the reads, so next iter's writes can't bypass this iter's reads.
  __shared__ __align__(16) unsigned short Plds[NWA][16][72];
  __shared__ float Ored[16][Dn];
  __shared__ float lred[16];

  const int tid  = threadIdx.x;
  const int wave = tid >> 6;
  const int lane = tid & 63;
  const int l    = lane & 15;
  const int quad = lane >> 4;
  const int qb   = blockIdx.x * 16;
  const int mbeg = blockIdx.y * BCOLS + wave * WCOLS;

  for (int i = tid; i < 16 * Dn; i += 256) ((float*)Ored)[i] = 0.0f;
  if (tid < 16) lred[tid] = 0.0f;
  __syncthreads();

  // Persistent Q A-fragments: A[m=l][k=quad*8+j], kk=0..3 covers D=128.
  bf16x8 aq[4];
  {
    const unsigned short* qrow = Qs + (size_t)(qb + l) * Dn + quad * 8;
#pragma unroll
    for (int kk = 0; kk < 4; ++kk)
      aq[kk] = *reinterpret_cast<const bf16x8*>(qrow + 32 * kk);
  }

  f32x4 O[8];                       // rows quad*4+r, cols 16n+l
#pragma unroll
  for (int n = 0; n < 8; ++n) O[n] = (f32x4){0.f, 0.f, 0.f, 0.f};
  float lsum[4] = {0.f, 0.f, 0.f, 0.f};

  // Software-pipelined W loads (one iteration ahead, nontemporal: W is
  // streamed exactly once -- don't evict L2-resident Kb/Vt).
  const float* wbase = W + (size_t)(qb + quad * 4) * Mn;
  float wcur[16], wnxt[16];
#pragma unroll
  for (int a = 0; a < 4; ++a)
#pragma unroll
    for (int r = 0; r < 4; ++r)
      wcur[a * 4 + r] =
          __builtin_nontemporal_load(wbase + (size_t)r * Mn + mbeg + 16 * a + l);

#pragma unroll
  for (int it = 0; it < NIT; ++it) {
    const int m0 = mbeg + it * NT;
    if (it + 1 < NIT) {
#pragma unroll
      for (int a = 0; a < 4; ++a)
#pragma unroll
        for (int r = 0; r < 4; ++r)
          wnxt[a * 4 + r] = __builtin_nontemporal_load(
              wbase + (size_t)r * Mn + m0 + NT + 16 * a + l);
    }

    // ---- S = (Q/sqrt(d)) K^T : 16 rows x 64 cols ----
    f32x4 S[4];
#pragma unroll
    for (int a = 0; a < 4; ++a) S[a] = (f32x4){0.f, 0.f, 0.f, 0.f};
#pragma unroll
    for (int a = 0; a < 4; ++a) {
      const unsigned short* krow = Kb + (size_t)(m0 + 16 * a + l) * Dn + quad * 8;
#pragma unroll
      for (int kk = 0; kk < 4; ++kk) {
        bf16x8 bk = *reinterpret_cast<const bf16x8*>(krow + 32 * kk);
        S[a] = __builtin_amdgcn_mfma_f32_16x16x32_bf16(aq[kk], bk, S[a], 0, 0, 0);
      }
    }

    // ---- p = exp(S*W); C-layout row=quad*4+r, col=16a+l ----
#pragma unroll
    for (int a = 0; a < 4; ++a) {
#pragma unroll
      for (int r = 0; r < 4; ++r) {
        float p = __expf(S[a][r] * wcur[a * 4 + r]);
        lsum[r] += p;
        Plds[wave][quad * 4 + r][16 * a + l] = f2bf(p);
      }
    }
    asm volatile("s_waitcnt lgkmcnt(0)" ::: "memory");

    // ---- O += P V : A-frag from LDS, B-frag Vt rows (16B contiguous) ----
#pragma unroll
    for (int kk = 0; kk < 2; ++kk) {
      bf16x8 pa = *reinterpret_cast<const bf16x8*>(
          &Plds[wave][l][32 * kk + quad * 8]);
#pragma unroll
      for (int n = 0; n < 8; ++n) {
        bf16x8 bv = *reinterpret_cast<const bf16x8*>(
            Vt + (size_t)(16 * n + l) * Mn + (m0 + 32 * kk + quad * 8));
        O[n] = __builtin_amdgcn_mfma_f32_16x16x32_bf16(pa, bv, O[n], 0, 0, 0);
      }
    }

#pragma unroll
    for (int i = 0; i < 16; ++i) wcur[i] = wnxt[i];
  }

  // Reduce lsum across the 16 lanes holding each row's columns.
#pragma unroll
  for (int r = 0; r < 4; ++r)
#pragma unroll
    for (int off = 1; off < 16; off <<= 1)
      lsum[r] += __shfl_xor(lsum[r], off, 64);

  // Cross-wave combine in LDS, then one global atomicAdd per element.
#pragma unroll
  for (int n = 0; n < 8; ++n)
#pragma unroll
    for (int r = 0; r < 4; ++r)
      atomicAdd(&Ored[quad * 4 + r][16 * n + l], O[n][r]);
  if (l == 0)
#pragma unroll
    for (int r = 0; r < 4; ++r) atomicAdd(&lred[quad * 4 + r], lsum[r]);
  __syncthreads();

  for (int i = tid; i < 16 * Dn; i += 256)
    atomicAdd(&Oacc[(size_t)qb * Dn + i], ((float*)Ored)[i]);
  if (tid < 16) atomicAdd(&Lacc[qb + tid], lred[tid]);
}

__global__ void finalize_kernel(const float4* __restrict__ Oacc,
                                const float* __restrict__ Lacc,
                                float4* __restrict__ out) {
  int i = blockIdx.x * blockDim.x + threadIdx.x;   // 0 .. Qn*Dn/4-1
  float4 o = Oacc[i];
  float inv = 1.0f / Lacc[i >> 5];                 // 32 float4 per row
  out[i] = make_float4(o.x * inv, o.y * inv, o.z * inv, o.w * inv);
}

extern "C" void kernel_launch(void* const* d_in, const int* in_sizes, int n_in,
                              void* d_out, int out_size, void* d_ws, size_t ws_size,
                              hipStream_t stream) {
  const float* Q = (const float*)d_in[0];          // [4096,128]
  const float* K = (const float*)d_in[1];          // [8192,128]
  const float* W = (const float*)d_in[2];          // [4096,8192]
  float* out = (float*)d_out;                      // [4096,128]

  unsigned short* Qs = (unsigned short*)d_ws;                 // 1 MB
  unsigned short* Kb = Qs + (size_t)Qn * Dn;                  // 2 MB
  unsigned short* Vt = Kb + (size_t)Mn * Dn;                  // 2 MB
  float* Oacc = (float*)(Vt + (size_t)Dn * Mn);               // 2 MB
  float* Lacc = Oacc + (size_t)Qn * Dn;                       // 16 KB  (contiguous after Oacc)

  // Zero the accumulators (ws is poisoned before every timed call).
  int n4 = (Qn * Dn + Qn) / 4;                                // 132096
  zero_kernel<<<(n4 + 255) / 256, 256, 0, stream>>>((float4*)Oacc, n4);

  cast_kernel<<<(Mn * Dn / 4) / 256, 256, 0, stream>>>(
      (const float4*)Q, (const float4*)K, (ushort4*)Qs, (ushort4*)Kb);
  transpose_kernel<<<dim3(Mn / 64, Dn / 64), 256, 0, stream>>>(K, Vt);

  attn_kernel<<<dim3(Qn / 16, MSPLIT), 256, 0, stream>>>(W, Qs, Kb, Vt, Oacc, Lacc);

  finalize_kernel<<<(Qn * Dn / 4) / 256, 256, 0, stream>>>(
      (const float4*)Oacc, Lacc, (float4*)out);
}